// Round 1
// 552.911 us; speedup vs baseline: 1.0126x; 1.0126x over previous
//
#include <hip/hip_runtime.h>

// Problem dims (fixed by harness)
#define NN 512
#define LL 1024
#define SS 3
#define DD 128
#define KK 4
#define HH 32
#define GG 64

// DPP ctrl encodings (gfx9/CDNA): cross-lane moves on the VALU pipe,
// replacing high-latency ds_swizzle for all intra-16-lane reduce stages.
#define DPP_XOR1 0xB1   // quad_perm [1,0,3,2]  == lane ^ 1
#define DPP_XOR2 0x4E   // quad_perm [2,3,0,1]  == lane ^ 2
#define DPP_ROR4 0x124  // row_ror:4  (rotate within 16-lane row; preserves k = r&3)
#define DPP_ROR8 0x128  // row_ror:8
// Only the 16-xor (crosses the two 16-lane rows of a 32-group) still needs LDS:
#define SWZ16 0x401F    // ds_swizzle BitMode xor-16 within 32-lane group

template <int CTRL>
__device__ __forceinline__ float dppf(float x) {
    return __int_as_float(__builtin_amdgcn_update_dpp(
        0, __float_as_int(x), CTRL, 0xF, 0xF, true));
}
__device__ __forceinline__ float swz16f(float x) {
    return __int_as_float(__builtin_amdgcn_ds_swizzle(__float_as_int(x), SWZ16));
}

// tanh-form GELU: max |err| vs exact erf-GELU ~3e-4 -- far under threshold.
__device__ __forceinline__ float fast_gelu(float x) {
    const float c0 = 0.7978845608028654f;
    const float c1 = 0.7978845608028654f * 0.044715f;
    float u = x * x;
    float y = x * fmaf(c1, u, c0);
    float e = __expf(2.0f * y);
    float r = __builtin_amdgcn_rcpf(e + 1.0f);
    float t = fmaf(-2.0f, r, 1.0f);
    return 0.5f * x * (1.0f + t);
}

// One block per n (512 blocks x 512 threads, 2 blocks/CU, 16 waves/CU).
// Phase A: mean over L of cust_repr[n] (+ scores staged to LDS, overlapped).
// Phase B: situation MLP, 256-sum split 4-way (chain depth 64, not 256).
// Phase C: 32 lanes/element, 4 element-chains in flight; all butterfly
// reduces on DPP (VALU) except one xor16 swizzle per ladder.
__global__ __launch_bounds__(512, 4) void k_all(
    const float* __restrict__ scores, const float* __restrict__ veh,
    const float* __restrict__ cust, const float* __restrict__ edge,
    const float* __restrict__ ew1, const float* __restrict__ eb1,
    const float* __restrict__ ew2, const float* __restrict__ eb2,
    const float* __restrict__ sw1, const float* __restrict__ sb1,
    const float* __restrict__ sw2, const float* __restrict__ sb2,
    const float* __restrict__ cand_w, const float* __restrict__ cand_b,
    const float* __restrict__ edge_w, const float* __restrict__ gbp,
    float* __restrict__ out)
{
    __shared__ float4 red[512];
    __shared__ float sin_[2 * DD];
    __shared__ float hg[GG];
    __shared__ float slds[KK];
    __shared__ float4 sc4[(LL * SS) / 4];   // 12 KB: block-n scores

    const int n = blockIdx.x;
    const int t = threadIdx.x;
    const int lane = t & 63;
    const int r = lane & 31;

    const int ko = r & 3;        // owned gate/expert channel
    const int jg = r >> 2;       // owned hidden quad (0..7)
    const bool kb0 = (r & 1) != 0;
    const bool kb1 = (r & 2) != 0;

    // ---- stage scores -> LDS (coalesced float4; overlaps Phase A stream) ----
    {
        const float4* sp4 = (const float4*)(scores + (size_t)n * LL * SS);
        sc4[t] = sp4[t];
        if (t < 256) sc4[512 + t] = sp4[512 + t];
    }

    // per-lane constant weights (latency hidden behind Phase A streaming)
    const float4* ew4 = (const float4*)edge_w;            // (D,K)
    const float4 wqa = ew4[4 * r + 0];
    const float4 wqb = ew4[4 * r + 1];
    const float4 wqc = ew4[4 * r + 2];
    const float4 wqd = ew4[4 * r + 3];
    const float cw0 = cand_w[0 * KK + ko];
    const float cw1 = cand_w[1 * KK + ko];
    const float cw2 = cand_w[2 * KK + ko];
    const float cb  = cand_b[ko];
    const float4* w1f = (const float4*)ew1;               // (K,S,H)
    const float4 w1a = w1f[(ko * SS + 0) * (HH / 4) + jg];
    const float4 w1b = w1f[(ko * SS + 1) * (HH / 4) + jg];
    const float4 w1c = w1f[(ko * SS + 2) * (HH / 4) + jg];
    const float4 b1v = ((const float4*)eb1)[ko * (HH / 4) + jg];
    const float4 w2v = ((const float4*)ew2)[ko * (HH / 4) + jg];
    const float b2o8 = 0.125f * eb2[ko];   // b2 folded into per-lane partial
    const float gbv = gbp[0];
    const float alpha = 1.0f / (1.0f + __expf(-gbv));
    const float onema = 1.0f - alpha;

    // ---- Phase A: mean over L of cust[n] ----
    const int c = t & 31;
    const int rs = t >> 5;
    const float4* cp = (const float4*)(cust + (size_t)n * LL * DD);
    float4 a0 = make_float4(0.f, 0.f, 0.f, 0.f), a1 = a0, a2 = a0, a3 = a0;
    #pragma unroll 4
    for (int i = 0; i < 16; ++i) {
        float4 v0 = cp[(rs + 16 * i      ) * 32 + c];
        float4 v1 = cp[(rs + 16 * i + 256) * 32 + c];
        float4 v2 = cp[(rs + 16 * i + 512) * 32 + c];
        float4 v3 = cp[(rs + 16 * i + 768) * 32 + c];
        a0.x += v0.x; a0.y += v0.y; a0.z += v0.z; a0.w += v0.w;
        a1.x += v1.x; a1.y += v1.y; a1.z += v1.z; a1.w += v1.w;
        a2.x += v2.x; a2.y += v2.y; a2.z += v2.z; a2.w += v2.w;
        a3.x += v3.x; a3.y += v3.y; a3.z += v3.z; a3.w += v3.w;
    }
    a0.x += a1.x + a2.x + a3.x;
    a0.y += a1.y + a2.y + a3.y;
    a0.z += a1.z + a2.z + a3.z;
    a0.w += a1.w + a2.w + a3.w;
    red[t] = a0;
    __syncthreads();

    if (t < 32) {
        float4 s = red[t];
        #pragma unroll
        for (int i = 1; i < 16; i++) {
            float4 v = red[i * 32 + t];
            s.x += v.x; s.y += v.y; s.z += v.z; s.w += v.w;
        }
        const float inv = 1.0f / (float)LL;
        sin_[DD + 4 * t + 0] = s.x * inv;
        sin_[DD + 4 * t + 1] = s.y * inv;
        sin_[DD + 4 * t + 2] = s.z * inv;
        sin_[DD + 4 * t + 3] = s.w * inv;
        float4 vv = ((const float4*)(veh + (size_t)n * DD))[t];
        sin_[4 * t + 0] = vv.x; sin_[4 * t + 1] = vv.y;
        sin_[4 * t + 2] = vv.z; sin_[4 * t + 3] = vv.w;
    }
    __syncthreads();

    // ---- Phase B: situation MLP (4-way split: chain depth 64, 256 threads) ----
    float* redf = (float*)red;
    if (t < 256) {
        const int g = t & 63;
        const int part = t >> 6;
        float a = 0.f;
        #pragma unroll 8
        for (int i = 0; i < 64; ++i) {
            const int row = part * 64 + i;
            a = fmaf(sin_[row], sw1[row * GG + g], a);
        }
        redf[t] = a;
    }
    __syncthreads();
    if (t < GG) {
        float a = sb1[t] + redf[t] + redf[t + 64] + redf[t + 128] + redf[t + 192];
        hg[t] = fast_gelu(a);
    }
    __syncthreads();
    if (t < KK) {
        float a = sb2[t];
        #pragma unroll
        for (int g = 0; g < GG; g++)
            a = fmaf(hg[g], sw2[g * KK + t], a);
        slds[t] = a;
    }
    __syncthreads();

    // hoisted per-n sit-logit select + alpha blend
    const float sl0 = slds[0], sl1 = slds[1], sl2 = slds[2], sl3 = slds[3];
    float sa_ = kb0 ? sl1 : sl0;
    float sb_ = kb0 ? sl3 : sl2;
    float so  = kb1 ? sb_ : sa_;
    const float sbase = fmaf(alpha, so, onema * cb);

    // ---- Phase C: 1024 elements, 4 chains in flight, DPP reduces ----
    const int base_el = t >> 5;   // 0..15
    const float* sc_lds = (const float*)sc4;
    const float* ed_base = edge + (size_t)n * LL * DD;
    float* out_base = out + (size_t)n * LL;

    for (int i = 0; i < 16; ++i) {
        const int e0 = base_el + i * 64;
        float4 ev[4];
        float s0[4], s1[4], s2[4];
        #pragma unroll
        for (int u = 0; u < 4; ++u)
            ev[u] = *(const float4*)(ed_base + (size_t)(e0 + u * 16) * DD + r * 4);
        #pragma unroll
        for (int u = 0; u < 4; ++u) {
            const int el = e0 + u * 16;   // uniform within 32-group -> LDS broadcast
            s0[u] = sc_lds[el * 3 + 0];
            s1[u] = sc_lds[el * 3 + 1];
            s2[u] = sc_lds[el * 3 + 2];
        }

        // edge-dot partials for all 4 k over the 4 owned dims
        float p0[4], p1[4], p2[4], p3[4];
        #pragma unroll
        for (int u = 0; u < 4; ++u) {
            p0[u] = fmaf(ev[u].x, wqa.x, fmaf(ev[u].y, wqb.x, fmaf(ev[u].z, wqc.x, ev[u].w * wqd.x)));
            p1[u] = fmaf(ev[u].x, wqa.y, fmaf(ev[u].y, wqb.y, fmaf(ev[u].z, wqc.y, ev[u].w * wqd.y)));
            p2[u] = fmaf(ev[u].x, wqa.z, fmaf(ev[u].y, wqb.z, fmaf(ev[u].z, wqc.z, ev[u].w * wqd.z)));
            p3[u] = fmaf(ev[u].x, wqa.w, fmaf(ev[u].y, wqb.w, fmaf(ev[u].z, wqc.w, ev[u].w * wqd.w)));
        }
        // butterfly exchange on DPP: xor1 (2 movs), xor2 (1 mov)
        float P0[4], P2[4];
        #pragma unroll
        for (int u = 0; u < 4; ++u) {
            float g0 = kb0 ? p0[u] : p1[u];
            float g2 = kb0 ? p2[u] : p3[u];
            float k0 = kb0 ? p1[u] : p0[u];
            float k2 = kb0 ? p3[u] : p2[u];
            P0[u] = k0 + dppf<DPP_XOR1>(g0);
            P2[u] = k2 + dppf<DPP_XOR1>(g2);
        }
        float q[4];
        #pragma unroll
        for (int u = 0; u < 4; ++u) {
            float gv = kb1 ? P0[u] : P2[u];
            float kv = kb1 ? P2[u] : P0[u];
            q[u] = kv + dppf<DPP_XOR2>(gv);
        }
        // rotate-accumulate covers all 4 quads of the 16-row, k-mapping intact
        #pragma unroll
        for (int u = 0; u < 4; ++u) q[u] += dppf<DPP_ROR4>(q[u]);
        #pragma unroll
        for (int u = 0; u < 4; ++u) q[u] += dppf<DPP_ROR8>(q[u]);
        #pragma unroll
        for (int u = 0; u < 4; ++u) q[u] += swz16f(q[u]);
        // q[u] = edge_dot[k=ko], replicated over the 8 lanes sharing ko

        // gate logit -> exp (no max-sub: |gl| ~ 3, fp32 exp is exact enough)
        float ex[4];
        #pragma unroll
        for (int u = 0; u < 4; ++u) {
            float sdot = fmaf(s0[u], cw0, fmaf(s1[u], cw1, s2[u] * cw2));
            float gl = fmaf(onema, sdot + q[u], sbase);
            ex[u] = __expf(gl);
        }
        float se[4];
        #pragma unroll
        for (int u = 0; u < 4; ++u) se[u] = ex[u] + dppf<DPP_XOR1>(ex[u]);
        #pragma unroll
        for (int u = 0; u < 4; ++u) se[u] += dppf<DPP_XOR2>(se[u]);

        // expert MLP: 4 hidden units of own k; fold gate weight + bias
        float tk[4];
        #pragma unroll
        for (int u = 0; u < 4; ++u) {
            float gw = ex[u] * __builtin_amdgcn_rcpf(se[u]);
            float z, h, acc;
            z = fmaf(s0[u], w1a.x, fmaf(s1[u], w1b.x, fmaf(s2[u], w1c.x, b1v.x))); h = fast_gelu(z); acc = h * w2v.x;
            z = fmaf(s0[u], w1a.y, fmaf(s1[u], w1b.y, fmaf(s2[u], w1c.y, b1v.y))); h = fast_gelu(z); acc = fmaf(h, w2v.y, acc);
            z = fmaf(s0[u], w1a.z, fmaf(s1[u], w1b.z, fmaf(s2[u], w1c.z, b1v.z))); h = fast_gelu(z); acc = fmaf(h, w2v.z, acc);
            z = fmaf(s0[u], w1a.w, fmaf(s1[u], w1b.w, fmaf(s2[u], w1c.w, b1v.w))); h = fast_gelu(z); acc = fmaf(h, w2v.w, acc);
            tk[u] = gw * (acc + b2o8);
        }
        // single full 32-lane reduce = sum over h-groups AND over k (DPP + 1 swz)
        #pragma unroll
        for (int u = 0; u < 4; ++u) tk[u] += dppf<DPP_XOR1>(tk[u]);
        #pragma unroll
        for (int u = 0; u < 4; ++u) tk[u] += dppf<DPP_XOR2>(tk[u]);
        #pragma unroll
        for (int u = 0; u < 4; ++u) tk[u] += dppf<DPP_ROR4>(tk[u]);
        #pragma unroll
        for (int u = 0; u < 4; ++u) tk[u] += dppf<DPP_ROR8>(tk[u]);
        #pragma unroll
        for (int u = 0; u < 4; ++u) tk[u] += swz16f(tk[u]);

        if (r == 0) {
            #pragma unroll
            for (int u = 0; u < 4; ++u)
                out_base[e0 + u * 16] = tk[u];
        }
    }
}

extern "C" void kernel_launch(void* const* d_in, const int* in_sizes, int n_in,
                              void* d_out, int out_size, void* d_ws, size_t ws_size,
                              hipStream_t stream)
{
    const float* scores = (const float*)d_in[0];
    const float* veh    = (const float*)d_in[1];
    const float* cust   = (const float*)d_in[2];
    const float* edge   = (const float*)d_in[3];
    const float* ew1    = (const float*)d_in[4];
    const float* eb1    = (const float*)d_in[5];
    const float* ew2    = (const float*)d_in[6];
    const float* eb2    = (const float*)d_in[7];
    const float* sw1    = (const float*)d_in[8];
    const float* sb1    = (const float*)d_in[9];
    const float* sw2    = (const float*)d_in[10];
    const float* sb2    = (const float*)d_in[11];
    const float* cw     = (const float*)d_in[12];
    const float* cb     = (const float*)d_in[13];
    const float* egw    = (const float*)d_in[14];
    const float* gb     = (const float*)d_in[15];
    float* out = (float*)d_out;

    hipLaunchKernelGGL(k_all, dim3(NN), dim3(512), 0, stream,
                       scores, veh, cust, edge, ew1, eb1, ew2, eb2,
                       sw1, sb1, sw2, sb2, cw, cb, egw, gb, out);
}

// Round 2
// 537.454 us; speedup vs baseline: 1.0417x; 1.0288x over previous
//
#include <hip/hip_runtime.h>

// Problem dims (fixed by harness)
#define NN 512
#define LL 1024
#define SS 3
#define DD 128
#define KK 4
#define HH 32
#define GG 64

// DPP ctrl encodings (gfx9/CDNA): cross-lane moves on the VALU pipe.
#define DPP_XOR1 0xB1   // quad_perm [1,0,3,2]  == lane ^ 1
#define DPP_XOR2 0x4E   // quad_perm [2,3,0,1]  == lane ^ 2
#define DPP_ROR4 0x124  // row_ror:4  (preserves k = r&3 class)
#define DPP_ROR8 0x128  // row_ror:8
#define SWZ16 0x401F    // ds_swizzle BitMode xor-16 within 32-lane group

template <int CTRL>
__device__ __forceinline__ float dppf(float x) {
    return __int_as_float(__builtin_amdgcn_update_dpp(
        0, __float_as_int(x), CTRL, 0xF, 0xF, true));
}
__device__ __forceinline__ float swz16f(float x) {
    return __int_as_float(__builtin_amdgcn_ds_swizzle(__float_as_int(x), SWZ16));
}

// tanh-form GELU: max |err| vs exact erf-GELU ~3e-4 -- far under threshold.
__device__ __forceinline__ float fast_gelu(float x) {
    const float c0 = 0.7978845608028654f;
    const float c1 = 0.7978845608028654f * 0.044715f;
    float u = x * x;
    float y = x * fmaf(c1, u, c0);
    float e = __expf(2.0f * y);
    float r = __builtin_amdgcn_rcpf(e + 1.0f);
    float t = fmaf(-2.0f, r, 1.0f);
    return 0.5f * x * (1.0f + t);
}

// One block per n. KEY RESTRUCTURE vs prior version: the softmax factorizes
// exp(a*sit + (1-a)*cand) = exp(a*sit) * exp((1-a)*cand), so the per-element
// work (edge-dot, cand exp, expert MLP) does NOT need the sit MLP result.
// We therefore run ONE fused main loop that streams BOTH cust (mean) and
// edge (per-element compute) with 8 float4 loads in flight, parking
// per-element {V_k = exc_k*expert_k, E_k = exc_k} in LDS. The sit MLP and a
// trivial normalize pass run after. This removes the serial memory phases
// that capped us at 19% HBM / 31% VALU.
__global__ __launch_bounds__(512, 4) void k_all(
    const float* __restrict__ scores, const float* __restrict__ veh,
    const float* __restrict__ cust, const float* __restrict__ edge,
    const float* __restrict__ ew1, const float* __restrict__ eb1,
    const float* __restrict__ ew2, const float* __restrict__ eb2,
    const float* __restrict__ sw1, const float* __restrict__ sb1,
    const float* __restrict__ sw2, const float* __restrict__ sb2,
    const float* __restrict__ cand_w, const float* __restrict__ cand_b,
    const float* __restrict__ edge_w, const float* __restrict__ gbp,
    float* __restrict__ out)
{
    __shared__ float4 red[512];
    __shared__ float sin_[2 * DD];
    __shared__ float hg[GG];
    __shared__ float slds[KK];
    __shared__ float4 sc4[(LL * SS) / 4];   // 12 KB: block-n scores
    __shared__ float elds[LL * 8];          // 32 KB: per-element {V0..3,E0..3}

    const int n = blockIdx.x;
    const int t = threadIdx.x;
    const int lane = t & 63;
    const int r = lane & 31;

    const int ko = r & 3;        // owned gate/expert channel
    const int jg = r >> 2;       // owned hidden quad (0..7)
    const bool kb0 = (r & 1) != 0;
    const bool kb1 = (r & 2) != 0;

    // ---- stage scores -> LDS (coalesced float4) ----
    {
        const float4* sp4 = (const float4*)(scores + (size_t)n * LL * SS);
        sc4[t] = sp4[t];
        if (t < 256) sc4[512 + t] = sp4[512 + t];
    }

    // per-lane constant weights (latency hidden behind staging)
    const float4* ew4 = (const float4*)edge_w;            // (D,K)
    const float4 wqa = ew4[4 * r + 0];
    const float4 wqb = ew4[4 * r + 1];
    const float4 wqc = ew4[4 * r + 2];
    const float4 wqd = ew4[4 * r + 3];
    const float cw0 = cand_w[0 * KK + ko];
    const float cw1 = cand_w[1 * KK + ko];
    const float cw2 = cand_w[2 * KK + ko];
    const float cb  = cand_b[ko];
    const float4* w1f = (const float4*)ew1;               // (K,S,H)
    const float4 w1a = w1f[(ko * SS + 0) * (HH / 4) + jg];
    const float4 w1b = w1f[(ko * SS + 1) * (HH / 4) + jg];
    const float4 w1c = w1f[(ko * SS + 2) * (HH / 4) + jg];
    const float4 b1v = ((const float4*)eb1)[ko * (HH / 4) + jg];
    const float4 w2v = ((const float4*)ew2)[ko * (HH / 4) + jg];
    const float b2o8 = 0.125f * eb2[ko];   // b2 folded into per-lane partial
    const float gbv = gbp[0];
    const float alpha = 1.0f / (1.0f + __expf(-gbv));
    const float onema = 1.0f - alpha;
    const float cbase = onema * cb;        // (1-a)*cand_b folded into exc

    __syncthreads();   // sc4 ready

    // ---- fused main loop: cust mean stream + per-element compute ----
    const int c = t & 31;
    const int rs = t >> 5;
    const float4* cp = (const float4*)(cust + (size_t)n * LL * DD);
    const int base_el = t >> 5;   // 0..15
    const float* sc_lds = (const float*)sc4;
    const float* ed_base = edge + (size_t)n * LL * DD;

    float4 a0 = make_float4(0.f, 0.f, 0.f, 0.f), a1 = a0, a2 = a0, a3 = a0;

    for (int i = 0; i < 16; ++i) {
        const int e0 = base_el + i * 64;

        // --- issue all 8 global loads up front (edge first, cust behind) ---
        float4 ev[4];
        #pragma unroll
        for (int u = 0; u < 4; ++u)
            ev[u] = *(const float4*)(ed_base + (size_t)(e0 + u * 16) * DD + r * 4);
        float4 v0 = cp[(rs + 16 * i      ) * 32 + c];
        float4 v1 = cp[(rs + 16 * i + 256) * 32 + c];
        float4 v2 = cp[(rs + 16 * i + 512) * 32 + c];
        float4 v3 = cp[(rs + 16 * i + 768) * 32 + c];

        float s0[4], s1[4], s2[4];
        #pragma unroll
        for (int u = 0; u < 4; ++u) {
            const int el = e0 + u * 16;   // uniform within 32-group -> broadcast
            s0[u] = sc_lds[el * 3 + 0];
            s1[u] = sc_lds[el * 3 + 1];
            s2[u] = sc_lds[el * 3 + 2];
        }

        // edge-dot partials for all 4 k over the 4 owned dims
        float p0[4], p1[4], p2[4], p3[4];
        #pragma unroll
        for (int u = 0; u < 4; ++u) {
            p0[u] = fmaf(ev[u].x, wqa.x, fmaf(ev[u].y, wqb.x, fmaf(ev[u].z, wqc.x, ev[u].w * wqd.x)));
            p1[u] = fmaf(ev[u].x, wqa.y, fmaf(ev[u].y, wqb.y, fmaf(ev[u].z, wqc.y, ev[u].w * wqd.y)));
            p2[u] = fmaf(ev[u].x, wqa.z, fmaf(ev[u].y, wqb.z, fmaf(ev[u].z, wqc.z, ev[u].w * wqd.z)));
            p3[u] = fmaf(ev[u].x, wqa.w, fmaf(ev[u].y, wqb.w, fmaf(ev[u].z, wqc.w, ev[u].w * wqd.w)));
        }
        // butterfly exchange on DPP: xor1, xor2
        float P0[4], P2[4];
        #pragma unroll
        for (int u = 0; u < 4; ++u) {
            float g0 = kb0 ? p0[u] : p1[u];
            float g2 = kb0 ? p2[u] : p3[u];
            float k0 = kb0 ? p1[u] : p0[u];
            float k2 = kb0 ? p3[u] : p2[u];
            P0[u] = k0 + dppf<DPP_XOR1>(g0);
            P2[u] = k2 + dppf<DPP_XOR1>(g2);
        }
        float q[4];
        #pragma unroll
        for (int u = 0; u < 4; ++u) {
            float gv = kb1 ? P0[u] : P2[u];
            float kv = kb1 ? P2[u] : P0[u];
            q[u] = kv + dppf<DPP_XOR2>(gv);
        }
        #pragma unroll
        for (int u = 0; u < 4; ++u) q[u] += dppf<DPP_ROR4>(q[u]);
        #pragma unroll
        for (int u = 0; u < 4; ++u) q[u] += dppf<DPP_ROR8>(q[u]);
        #pragma unroll
        for (int u = 0; u < 4; ++u) q[u] += swz16f(q[u]);
        // q[u] = edge_dot[k=ko], replicated over the 8 lanes sharing ko

        // candidate-side exponential (sit part deferred; factorized softmax)
        float exc[4];
        #pragma unroll
        for (int u = 0; u < 4; ++u) {
            float sdot = fmaf(s0[u], cw0, fmaf(s1[u], cw1, s2[u] * cw2));
            exc[u] = __expf(fmaf(onema, sdot + q[u], cbase));
        }

        // expert MLP: 4 hidden units of own k; weight by exc, fold b2
        float vq[4];
        #pragma unroll
        for (int u = 0; u < 4; ++u) {
            float z, h, acc;
            z = fmaf(s0[u], w1a.x, fmaf(s1[u], w1b.x, fmaf(s2[u], w1c.x, b1v.x))); h = fast_gelu(z); acc = h * w2v.x;
            z = fmaf(s0[u], w1a.y, fmaf(s1[u], w1b.y, fmaf(s2[u], w1c.y, b1v.y))); h = fast_gelu(z); acc = fmaf(h, w2v.y, acc);
            z = fmaf(s0[u], w1a.z, fmaf(s1[u], w1b.z, fmaf(s2[u], w1c.z, b1v.z))); h = fast_gelu(z); acc = fmaf(h, w2v.z, acc);
            z = fmaf(s0[u], w1a.w, fmaf(s1[u], w1b.w, fmaf(s2[u], w1c.w, b1v.w))); h = fast_gelu(z); acc = fmaf(h, w2v.w, acc);
            vq[u] = exc[u] * (acc + b2o8);
        }
        // sum over the 8 jg lanes within each k (ror4+ror8+xor16)
        #pragma unroll
        for (int u = 0; u < 4; ++u) vq[u] += dppf<DPP_ROR4>(vq[u]);
        #pragma unroll
        for (int u = 0; u < 4; ++u) vq[u] += dppf<DPP_ROR8>(vq[u]);
        #pragma unroll
        for (int u = 0; u < 4; ++u) vq[u] += swz16f(vq[u]);
        // lane r<4 now holds V_k (k=r); exc replicated over jg

        // park {V_k, E_k} in LDS (lanes r and r+32 hit same bank: 2-way = free)
        if (r < 8) {
            #pragma unroll
            for (int u = 0; u < 4; ++u) {
                const int el = e0 + u * 16;
                elds[el * 8 + r] = (r < 4) ? vq[u] : exc[u];
            }
        }

        // cust mean accumulation (loads long since landed)
        a0.x += v0.x; a0.y += v0.y; a0.z += v0.z; a0.w += v0.w;
        a1.x += v1.x; a1.y += v1.y; a1.z += v1.z; a1.w += v1.w;
        a2.x += v2.x; a2.y += v2.y; a2.z += v2.z; a2.w += v2.w;
        a3.x += v3.x; a3.y += v3.y; a3.z += v3.z; a3.w += v3.w;
    }

    a0.x += a1.x + a2.x + a3.x;
    a0.y += a1.y + a2.y + a3.y;
    a0.z += a1.z + a2.z + a3.z;
    a0.w += a1.w + a2.w + a3.w;
    red[t] = a0;
    __syncthreads();

    if (t < 32) {
        float4 s = red[t];
        #pragma unroll
        for (int i = 1; i < 16; i++) {
            float4 v = red[i * 32 + t];
            s.x += v.x; s.y += v.y; s.z += v.z; s.w += v.w;
        }
        const float inv = 1.0f / (float)LL;
        sin_[DD + 4 * t + 0] = s.x * inv;
        sin_[DD + 4 * t + 1] = s.y * inv;
        sin_[DD + 4 * t + 2] = s.z * inv;
        sin_[DD + 4 * t + 3] = s.w * inv;
        float4 vv = ((const float4*)(veh + (size_t)n * DD))[t];
        sin_[4 * t + 0] = vv.x; sin_[4 * t + 1] = vv.y;
        sin_[4 * t + 2] = vv.z; sin_[4 * t + 3] = vv.w;
    }
    __syncthreads();

    // ---- situation MLP (4-way split: chain depth 64) ----
    float* redf = (float*)red;
    if (t < 256) {
        const int g = t & 63;
        const int part = t >> 6;
        float a = 0.f;
        #pragma unroll 8
        for (int i = 0; i < 64; ++i) {
            const int row = part * 64 + i;
            a = fmaf(sin_[row], sw1[row * GG + g], a);
        }
        redf[t] = a;
    }
    __syncthreads();
    if (t < GG) {
        float a = sb1[t] + redf[t] + redf[t + 64] + redf[t + 128] + redf[t + 192];
        hg[t] = fast_gelu(a);
    }
    __syncthreads();
    if (t < KK) {
        float a = sb2[t];
        #pragma unroll
        for (int g = 0; g < GG; g++)
            a = fmaf(hg[g], sw2[g * KK + t], a);
        slds[t] = a;
    }
    __syncthreads();

    // ---- final normalize: out = sum_k m_k V_k / sum_k m_k E_k ----
    const float m0 = __expf(alpha * slds[0]);
    const float m1 = __expf(alpha * slds[1]);
    const float m2 = __expf(alpha * slds[2]);
    const float m3 = __expf(alpha * slds[3]);
    float* out_base = out + (size_t)n * LL;
    #pragma unroll
    for (int e = t; e < LL; e += 512) {
        const float4 V = *(const float4*)&elds[e * 8];
        const float4 E = *(const float4*)&elds[e * 8 + 4];
        float num = fmaf(m0, V.x, fmaf(m1, V.y, fmaf(m2, V.z, m3 * V.w)));
        float den = fmaf(m0, E.x, fmaf(m1, E.y, fmaf(m2, E.z, m3 * E.w)));
        out_base[e] = num * __builtin_amdgcn_rcpf(den);
    }
}

extern "C" void kernel_launch(void* const* d_in, const int* in_sizes, int n_in,
                              void* d_out, int out_size, void* d_ws, size_t ws_size,
                              hipStream_t stream)
{
    const float* scores = (const float*)d_in[0];
    const float* veh    = (const float*)d_in[1];
    const float* cust   = (const float*)d_in[2];
    const float* edge   = (const float*)d_in[3];
    const float* ew1    = (const float*)d_in[4];
    const float* eb1    = (const float*)d_in[5];
    const float* ew2    = (const float*)d_in[6];
    const float* eb2    = (const float*)d_in[7];
    const float* sw1    = (const float*)d_in[8];
    const float* sb1    = (const float*)d_in[9];
    const float* sw2    = (const float*)d_in[10];
    const float* sb2    = (const float*)d_in[11];
    const float* cw     = (const float*)d_in[12];
    const float* cb     = (const float*)d_in[13];
    const float* egw    = (const float*)d_in[14];
    const float* gb     = (const float*)d_in[15];
    float* out = (float*)d_out;

    hipLaunchKernelGGL(k_all, dim3(NN), dim3(512), 0, stream,
                       scores, veh, cust, edge, ew1, eb1, ew2, eb2,
                       sw1, sb1, sw2, sb2, cw, cb, egw, gb, out);
}